// Round 1
// baseline (168.790 us; speedup 1.0000x reference)
//
#include <hip/hip_runtime.h>
#include <math.h>

// Problem constants
#define M_ROWS 7680      // bs(4) * seq(32) * 60 patches
#define N1 512
#define K1 1024
#define NPX 160
#define NPY 96
#define BDIM 128         // bs*seq
#define NPATCH 60

// ws float offsets
#define OFF_WGEFF   0                       // 512*3 floats
#define OFF_BIASEFF 1536                    // 3 floats
#define OFF_HWPART  2048                    // 8 * 7680 * 3 floats
#define OFF_HW      (2048 + 8*M_ROWS*3)     // 7680*3 floats

// ---------------------------------------------------------------------------
// Fold Wg_eff[j,c] = sum_k W2[j,k]*Wg[k,c]  (512x3), bias_eff[c] = b2 @ Wg[:128,c]
__global__ __launch_bounds__(512) void precompute_kernel(
    const float* __restrict__ W2, const float* __restrict__ b2,
    const float* __restrict__ Wg, float* __restrict__ ws)
{
    int j = threadIdx.x;   // 0..511
    float a0 = 0.f, a1 = 0.f, a2 = 0.f;
    for (int k = 0; k < 128; ++k) {
        float w = W2[j * 128 + k];
        a0 = fmaf(w, Wg[k * 3 + 0], a0);
        a1 = fmaf(w, Wg[k * 3 + 1], a1);
        a2 = fmaf(w, Wg[k * 3 + 2], a2);
    }
    ws[OFF_WGEFF + j * 3 + 0] = a0;
    ws[OFF_WGEFF + j * 3 + 1] = a1;
    ws[OFF_WGEFF + j * 3 + 2] = a2;
    if (j < 3) {
        float s = 0.f;
        for (int k = 0; k < 128; ++k) s = fmaf(b2[k], Wg[k * 3 + j], s);
        ws[OFF_BIASEFF + j] = s;
    }
}

// ---------------------------------------------------------------------------
// C = softplus(PV @ W1 + b1); then reduce over this block's 64 N-columns with
// Wg_eff -> hw_part[jblk][row][3].  64x64 tile, 256 threads, 4x4 microtile.
__global__ __launch_bounds__(256) void gemm_softplus_kernel(
    const float* __restrict__ A,    // [7680,1024]
    const float* __restrict__ W1,   // [1024,512]
    const float* __restrict__ b1,   // [512]
    const float* __restrict__ ws,   // Wg_eff at OFF_WGEFF
    float* __restrict__ hw_part)    // [8][7680][3]
{
    __shared__ float As[16][64];        // transposed A tile: As[k][m]
    __shared__ float Bs[16][64];        // Bs[k][n]
    __shared__ float red[16][16][12];   // [ty][tx][i*3+c]

    const int tid = threadIdx.x;
    const int tx = tid & 15, ty = tid >> 4;
    const int row0 = blockIdx.x * 64;
    const int n0 = blockIdx.y * 64;

    // load mappings
    const int lm  = tid >> 2;           // 0..63  A row in tile
    const int lk  = (tid & 3) << 2;     // 0,4,8,12 k offset
    const int lkB = tid >> 4;           // 0..15  B k in tile
    const int lnB = (tid & 15) << 2;    // 0..60  B n offset

    float acc[4][4] = {{0.f}};
    const float* Aptr = A + (size_t)(row0 + lm) * K1 + lk;
    const float* Bptr = W1 + (size_t)lkB * N1 + n0 + lnB;

    for (int k0 = 0; k0 < K1; k0 += 16) {
        float4 av = *(const float4*)(Aptr + k0);
        float4 bv = *(const float4*)(Bptr + (size_t)k0 * N1);
        __syncthreads();
        As[lk + 0][lm] = av.x;
        As[lk + 1][lm] = av.y;
        As[lk + 2][lm] = av.z;
        As[lk + 3][lm] = av.w;
        *(float4*)&Bs[lkB][lnB] = bv;
        __syncthreads();
#pragma unroll
        for (int k = 0; k < 16; ++k) {
            float4 a4 = *(const float4*)&As[k][ty * 4];
            float4 b4 = *(const float4*)&Bs[k][tx * 4];
            float av_[4] = {a4.x, a4.y, a4.z, a4.w};
            float bv_[4] = {b4.x, b4.y, b4.z, b4.w};
#pragma unroll
            for (int i = 0; i < 4; ++i)
#pragma unroll
                for (int j = 0; j < 4; ++j)
                    acc[i][j] = fmaf(av_[i], bv_[j], acc[i][j]);
        }
    }

    // epilogue: softplus + multiply by Wg_eff, reduce over this thread's 4 cols
    float part[4][3] = {{0.f}};
#pragma unroll
    for (int j = 0; j < 4; ++j) {
        int n = n0 + tx * 4 + j;
        float bb = b1[n];
        float wg0 = ws[OFF_WGEFF + n * 3 + 0];
        float wg1 = ws[OFF_WGEFF + n * 3 + 1];
        float wg2 = ws[OFF_WGEFF + n * 3 + 2];
#pragma unroll
        for (int i = 0; i < 4; ++i) {
            float z = acc[i][j] + bb;
            float sp = fmaxf(z, 0.f) + log1pf(expf(-fabsf(z)));   // stable softplus
            part[i][0] = fmaf(sp, wg0, part[i][0]);
            part[i][1] = fmaf(sp, wg1, part[i][1]);
            part[i][2] = fmaf(sp, wg2, part[i][2]);
        }
    }
    __syncthreads();
#pragma unroll
    for (int i = 0; i < 4; ++i)
#pragma unroll
        for (int c = 0; c < 3; ++c)
            red[ty][tx][i * 3 + c] = part[i][c];
    __syncthreads();
    // 192 threads: reduce across tx (deterministic order)
    if (tid < 192) {
        int r = tid / 3, c = tid - r * 3;   // r: row in tile 0..63
        int tyr = r >> 2, ir = r & 3;
        float s = 0.f;
#pragma unroll
        for (int t = 0; t < 16; ++t) s += red[tyr][t][ir * 3 + c];
        hw_part[((size_t)blockIdx.y * M_ROWS + row0 + r) * 3 + c] = s;
    }
}

// ---------------------------------------------------------------------------
// hw[p,c] = bias_eff[c] + sum_jb hw_part[jb][p][c]
__global__ __launch_bounds__(256) void hw_reduce_kernel(float* __restrict__ ws)
{
    int idx = blockIdx.x * 256 + threadIdx.x;
    if (idx >= M_ROWS * 3) return;
    int c = idx % 3;
    float s = ws[OFF_BIASEFF + c];
#pragma unroll
    for (int jb = 0; jb < 8; ++jb) s += ws[OFF_HWPART + jb * M_ROWS * 3 + idx];
    ws[OFF_HW + idx] = s;
}

// ---------------------------------------------------------------------------
// GCN as a 4-neighbor grid stencil.  xw(node) = hw[patch] + coord terms.
__global__ __launch_bounds__(256) void stencil_kernel(
    const float* __restrict__ ws, const float* __restrict__ Wg,
    const float* __restrict__ bg, float* __restrict__ out)
{
    int idx = blockIdx.x * 256 + threadIdx.x;
    if (idx >= BDIM * NPX * NPY) return;
    int y = idx % NPY;
    int t = idx / NPY;
    int x = t % NPX;
    int b = t / NPX;

    const float* hw = ws + OFF_HW;
    float wpx[3], wpy[3], wqx[3], wqy[3];
#pragma unroll
    for (int c = 0; c < 3; ++c) {
        wpx[c] = Wg[128 * 3 + c];
        wpy[c] = Wg[129 * 3 + c];
        wqx[c] = Wg[130 * 3 + c];
        wqy[c] = Wg[131 * 3 + c];
    }

    auto xwf = [&](int xx, int yy, float* o) {
        int pxp = xx >> 4, pyp = yy >> 4;
        const float* h = hw + ((size_t)b * NPATCH + pxp * 6 + pyp) * 3;
        float fx = (float)pxp, fy = (float)pyp;
        float gx = (float)(xx & 15) * (1.f / 15.f);
        float gy = (float)(yy & 15) * (1.f / 15.f);
#pragma unroll
        for (int c = 0; c < 3; ++c)
            o[c] = h[c] + fx * wpx[c] + fy * wpy[c] + gx * wqx[c] + gy * wqy[c];
    };

    float degc = 1.f + (x > 0) + (x < NPX - 1) + (y > 0) + (y < NPY - 1);
    float dinvc = rsqrtf(degc);

    float s0 = 0.f, s1 = 0.f, s2 = 0.f;
    float tmp[3];
    auto addn = [&](int xx, int yy) {
        float degn = 1.f + (xx > 0) + (xx < NPX - 1) + (yy > 0) + (yy < NPY - 1);
        float dinvn = rsqrtf(degn);
        xwf(xx, yy, tmp);
        s0 = fmaf(dinvn, tmp[0], s0);
        s1 = fmaf(dinvn, tmp[1], s1);
        s2 = fmaf(dinvn, tmp[2], s2);
    };
    if (x > 0)       addn(x - 1, y);
    if (x < NPX - 1) addn(x + 1, y);
    if (y > 0)       addn(x, y - 1);
    if (y < NPY - 1) addn(x, y + 1);

    float self[3];
    xwf(x, y, self);
    float inv_deg = 1.f / degc;
    out[(size_t)idx * 3 + 0] = fmaf(dinvc, s0, self[0] * inv_deg) + bg[0];
    out[(size_t)idx * 3 + 1] = fmaf(dinvc, s1, self[1] * inv_deg) + bg[1];
    out[(size_t)idx * 3 + 2] = fmaf(dinvc, s2, self[2] * inv_deg) + bg[2];
}

// ---------------------------------------------------------------------------
extern "C" void kernel_launch(void* const* d_in, const int* in_sizes, int n_in,
                              void* d_out, int out_size, void* d_ws, size_t ws_size,
                              hipStream_t stream) {
    const float* pv = (const float*)d_in[0];
    const float* W1 = (const float*)d_in[1];
    const float* b1 = (const float*)d_in[2];
    const float* W2 = (const float*)d_in[3];
    const float* b2 = (const float*)d_in[4];
    const float* Wg = (const float*)d_in[5];
    const float* bg = (const float*)d_in[6];
    // d_in[7] = edge_index: not needed (fixed 4-neighbor grid, derived analytically)

    float* ws = (float*)d_ws;
    float* out = (float*)d_out;

    hipLaunchKernelGGL(precompute_kernel, dim3(1), dim3(512), 0, stream,
                       W2, b2, Wg, ws);
    hipLaunchKernelGGL(gemm_softplus_kernel, dim3(120, 8), dim3(256), 0, stream,
                       pv, W1, b1, ws, ws + OFF_HWPART);
    hipLaunchKernelGGL(hw_reduce_kernel, dim3((M_ROWS * 3 + 255) / 256), dim3(256), 0, stream,
                       ws);
    hipLaunchKernelGGL(stencil_kernel, dim3((BDIM * NPX * NPY + 255) / 256), dim3(256), 0, stream,
                       ws, Wg, bg, out);
}

// Round 2
// 69.540 us; speedup vs baseline: 2.4272x; 2.4272x over previous
//
#include <hip/hip_runtime.h>
#include <math.h>

typedef __bf16 bf16_t;
typedef __bf16 bf16x8 __attribute__((ext_vector_type(8)));
typedef float f32x4 __attribute__((ext_vector_type(4)));

// Problem constants
#define M_ROWS 7680      // bs(4) * seq(32) * 60 patches
#define N1 512
#define K1 1024
#define NPX 160
#define NPY 96
#define BDIM 128         // bs*seq
#define NPATCH 60

// ws float offsets
#define OFF_WGEFF   0                       // 512*3 floats
#define OFF_BIASEFF 1536                    // 3 floats (+ pad to 2048)
#define OFF_HWPART  2048                    // 4 * 7680 * 3 floats = 92160
#define OFF_HW      (2048 + 4*M_ROWS*3)     // 94208, 23040 floats
#define OFF_W1T     (OFF_HW + M_ROWS*3)     // 117248 floats -> bf16[512*1024] = 1 MB

// GEMM tiling
#define BM 128
#define BN 128
#define BK 32
#define LDT 40           // padded LDS row length (bf16 elems); 80 B -> ~2-way banks (free)

// ---------------------------------------------------------------------------
// Wg_eff[j,c] = sum_k W2[j,k]*Wg[k,c]  (512x3), bias_eff[c] = b2 @ Wg[:128,c]
__global__ __launch_bounds__(512) void precompute_kernel(
    const float* __restrict__ W2, const float* __restrict__ b2,
    const float* __restrict__ Wg, float* __restrict__ ws)
{
    int j = threadIdx.x;   // 0..511
    float a0 = 0.f, a1 = 0.f, a2 = 0.f;
    for (int k = 0; k < 128; ++k) {
        float w = W2[j * 128 + k];
        a0 = fmaf(w, Wg[k * 3 + 0], a0);
        a1 = fmaf(w, Wg[k * 3 + 1], a1);
        a2 = fmaf(w, Wg[k * 3 + 2], a2);
    }
    ws[OFF_WGEFF + j * 3 + 0] = a0;
    ws[OFF_WGEFF + j * 3 + 1] = a1;
    ws[OFF_WGEFF + j * 3 + 2] = a2;
    if (j < 3) {
        float s = 0.f;
        for (int k = 0; k < 128; ++k) s = fmaf(b2[k], Wg[k * 3 + j], s);
        ws[OFF_BIASEFF + j] = s;
    }
}

// ---------------------------------------------------------------------------
// W1 [1024][512] f32  ->  W1T [512][1024] bf16 (LDS-tiled transpose)
__global__ __launch_bounds__(256) void w1t_kernel(
    const float* __restrict__ W1, bf16_t* __restrict__ W1T)
{
    __shared__ bf16_t tile[64][72];
    const int k0 = blockIdx.x * 64;   // 16 blocks
    const int n0 = blockIdx.y * 64;   // 8 blocks
    const int t = threadIdx.x;
#pragma unroll
    for (int i = 0; i < 4; ++i) {
        int idx = t + i * 256;
        int r = idx >> 4, ch = idx & 15;
        float4 v = *(const float4*)(W1 + (size_t)(k0 + r) * N1 + n0 + ch * 4);
        bf16_t* dst = &tile[r][ch * 4];
        dst[0] = (bf16_t)v.x; dst[1] = (bf16_t)v.y;
        dst[2] = (bf16_t)v.z; dst[3] = (bf16_t)v.w;
    }
    __syncthreads();
#pragma unroll
    for (int i = 0; i < 2; ++i) {
        int idx = t + i * 256;
        int nr = idx >> 3, kc = idx & 7;
        bf16x8 o;
#pragma unroll
        for (int j = 0; j < 8; ++j) o[j] = tile[kc * 8 + j][nr];
        *(bf16x8*)(W1T + (size_t)(n0 + nr) * K1 + k0 + kc * 8) = o;
    }
}

// ---------------------------------------------------------------------------
static __device__ inline bf16x8 cvt8(float4 a, float4 b) {
    bf16x8 v;
    v[0] = (bf16_t)a.x; v[1] = (bf16_t)a.y; v[2] = (bf16_t)a.z; v[3] = (bf16_t)a.w;
    v[4] = (bf16_t)b.x; v[5] = (bf16_t)b.y; v[6] = (bf16_t)b.z; v[7] = (bf16_t)b.w;
    return v;
}

// MFMA GEMM: z = A @ W1 (via W1T), fused softplus + Wg_eff fold -> hw_part.
// 128x128 tile, BK=32, 4 waves (each 64x64 = 4x4 frags of 16x16x32 bf16).
__global__ __launch_bounds__(256) void gemm_mfma_kernel(
    const float* __restrict__ A,      // [7680,1024] f32
    const bf16_t* __restrict__ W1T,   // [512,1024] bf16
    const float* __restrict__ b1,     // [512]
    const float* __restrict__ ws,     // Wg_eff at OFF_WGEFF
    float* __restrict__ hw_part)      // [4][7680][3]
{
    __shared__ __align__(16) char smem[49152];
    bf16_t* sA = (bf16_t*)smem;             // [2][128][40]  (20480 B)
    bf16_t* sB = sA + 2 * BM * LDT;         // [2][128][40]  (20480 B)
    float* red = (float*)smem;              // [128][32][3]  (49152 B, reused)

    const int t = threadIdx.x;
    const int lane = t & 63;
    const int wv = t >> 6;
    const int wr = wv >> 1, wc = wv & 1;
    const int l15 = lane & 15, hi = lane >> 4;

    const int m0 = blockIdx.x * BM;
    const int n0 = blockIdx.y * BN;

    // staging mapping: thread t -> row t>>1 (0..127), half t&1 (16 elems of k)
    const int srow = t >> 1;
    const int shalf = t & 1;
    const float*  aptr = A   + (size_t)(m0 + srow) * K1 + shalf * 16;
    const bf16_t* bptr = W1T + (size_t)(n0 + srow) * K1 + shalf * 16;
    const int swoff = srow * LDT + shalf * 16;

    // fragment read offsets (elements within one [128][40] buffer)
    int aoff[4], boff[4];
#pragma unroll
    for (int i = 0; i < 4; ++i) {
        aoff[i] = (wr * 64 + i * 16 + l15) * LDT + hi * 8;
        boff[i] = (wc * 64 + i * 16 + l15) * LDT + hi * 8;
    }

    f32x4 acc[4][4];
#pragma unroll
    for (int i = 0; i < 4; ++i)
#pragma unroll
        for (int j = 0; j < 4; ++j) acc[i][j] = (f32x4)0.f;

    // prologue: stage ks=0 into buffer 0
    {
        float4 fa0 = *(const float4*)(aptr + 0);
        float4 fa1 = *(const float4*)(aptr + 4);
        float4 fa2 = *(const float4*)(aptr + 8);
        float4 fa3 = *(const float4*)(aptr + 12);
        uint4  ub0 = *(const uint4*)(bptr);
        uint4  ub1 = *(const uint4*)(bptr + 8);
        *(bf16x8*)(sA + swoff)     = cvt8(fa0, fa1);
        *(bf16x8*)(sA + swoff + 8) = cvt8(fa2, fa3);
        *(uint4*)(sB + swoff)      = ub0;
        *(uint4*)(sB + swoff + 8)  = ub1;
    }
    __syncthreads();

    int cur = 0;
    for (int ks = 0; ks < K1 / BK; ++ks) {
        float4 fa0, fa1, fa2, fa3; uint4 ub0, ub1;
        const bool pf = (ks < K1 / BK - 1);
        if (pf) {
            const float*  ap = aptr + (ks + 1) * BK;
            const bf16_t* bp = bptr + (ks + 1) * BK;
            fa0 = *(const float4*)(ap + 0);
            fa1 = *(const float4*)(ap + 4);
            fa2 = *(const float4*)(ap + 8);
            fa3 = *(const float4*)(ap + 12);
            ub0 = *(const uint4*)(bp);
            ub1 = *(const uint4*)(bp + 8);
        }
        const bf16_t* cA = sA + cur * (BM * LDT);
        const bf16_t* cB = sB + cur * (BM * LDT);
        bf16x8 af[4], bfr[4];
#pragma unroll
        for (int i = 0; i < 4; ++i) {
            af[i]  = *(const bf16x8*)(cA + aoff[i]);
            bfr[i] = *(const bf16x8*)(cB + boff[i]);
        }
#pragma unroll
        for (int mi = 0; mi < 4; ++mi)
#pragma unroll
            for (int ni = 0; ni < 4; ++ni)
                acc[mi][ni] = __builtin_amdgcn_mfma_f32_16x16x32_bf16(
                    af[mi], bfr[ni], acc[mi][ni], 0, 0, 0);
        __syncthreads();
        if (pf) {
            bf16_t* nA = sA + (cur ^ 1) * (BM * LDT);
            bf16_t* nB = sB + (cur ^ 1) * (BM * LDT);
            *(bf16x8*)(nA + swoff)     = cvt8(fa0, fa1);
            *(bf16x8*)(nA + swoff + 8) = cvt8(fa2, fa3);
            *(uint4*)(nB + swoff)      = ub0;
            *(uint4*)(nB + swoff + 8)  = ub1;
            cur ^= 1;
        }
        __syncthreads();
    }

    // epilogue: softplus + Wg_eff fold; per-lane partials -> LDS -> hw_part
    float b1v[4], wgv[4][3];
#pragma unroll
    for (int ni = 0; ni < 4; ++ni) {
        int n = n0 + wc * 64 + ni * 16 + l15;
        b1v[ni]    = b1[n];
        wgv[ni][0] = ws[OFF_WGEFF + n * 3 + 0];
        wgv[ni][1] = ws[OFF_WGEFF + n * 3 + 1];
        wgv[ni][2] = ws[OFF_WGEFF + n * 3 + 2];
    }
#pragma unroll
    for (int mi = 0; mi < 4; ++mi)
#pragma unroll
        for (int r = 0; r < 4; ++r) {
            float p0 = 0.f, p1 = 0.f, p2 = 0.f;
#pragma unroll
            for (int ni = 0; ni < 4; ++ni) {
                float z = acc[mi][ni][r] + b1v[ni];
                float sp = fmaxf(z, 0.f) + __logf(1.f + __expf(-fabsf(z)));
                p0 = fmaf(sp, wgv[ni][0], p0);
                p1 = fmaf(sp, wgv[ni][1], p1);
                p2 = fmaf(sp, wgv[ni][2], p2);
            }
            int ml = wr * 64 + mi * 16 + hi * 4 + r;   // m-row in tile (bijective)
            int j  = wc * 16 + l15;                    // contributor 0..31
            float* dst = red + (ml * 32 + j) * 3;
            dst[0] = p0; dst[1] = p1; dst[2] = p2;
        }
    __syncthreads();
    for (int idx = t; idx < BM * 3; idx += 256) {
        int m = idx / 3, c = idx - m * 3;
        float s = 0.f;
#pragma unroll
        for (int j = 0; j < 32; ++j) s += red[(m * 32 + j) * 3 + c];
        hw_part[((size_t)blockIdx.y * M_ROWS + m0 + m) * 3 + c] = s;
    }
}

// ---------------------------------------------------------------------------
// hw[p,c] = bias_eff[c] + sum_jb hw_part[jb][p][c]
__global__ __launch_bounds__(256) void hw_reduce_kernel(float* __restrict__ ws)
{
    int idx = blockIdx.x * 256 + threadIdx.x;
    if (idx >= M_ROWS * 3) return;
    int c = idx % 3;
    float s = ws[OFF_BIASEFF + c];
#pragma unroll
    for (int jb = 0; jb < 4; ++jb) s += ws[OFF_HWPART + jb * M_ROWS * 3 + idx];
    ws[OFF_HW + idx] = s;
}

// ---------------------------------------------------------------------------
// GCN as a 4-neighbor grid stencil.  xw(node) = hw[patch] + coord terms.
__global__ __launch_bounds__(256) void stencil_kernel(
    const float* __restrict__ ws, const float* __restrict__ Wg,
    const float* __restrict__ bg, float* __restrict__ out)
{
    int idx = blockIdx.x * 256 + threadIdx.x;
    if (idx >= BDIM * NPX * NPY) return;
    int y = idx % NPY;
    int t = idx / NPY;
    int x = t % NPX;
    int b = t / NPX;

    const float* hw = ws + OFF_HW;
    float wpx[3], wpy[3], wqx[3], wqy[3];
#pragma unroll
    for (int c = 0; c < 3; ++c) {
        wpx[c] = Wg[128 * 3 + c];
        wpy[c] = Wg[129 * 3 + c];
        wqx[c] = Wg[130 * 3 + c];
        wqy[c] = Wg[131 * 3 + c];
    }

    auto xwf = [&](int xx, int yy, float* o) {
        int pxp = xx >> 4, pyp = yy >> 4;
        const float* h = hw + ((size_t)b * NPATCH + pxp * 6 + pyp) * 3;
        float fx = (float)pxp, fy = (float)pyp;
        float gx = (float)(xx & 15) * (1.f / 15.f);
        float gy = (float)(yy & 15) * (1.f / 15.f);
#pragma unroll
        for (int c = 0; c < 3; ++c)
            o[c] = h[c] + fx * wpx[c] + fy * wpy[c] + gx * wqx[c] + gy * wqy[c];
    };

    float degc = 1.f + (x > 0) + (x < NPX - 1) + (y > 0) + (y < NPY - 1);
    float dinvc = rsqrtf(degc);

    float s0 = 0.f, s1 = 0.f, s2 = 0.f;
    float tmp[3];
    auto addn = [&](int xx, int yy) {
        float degn = 1.f + (xx > 0) + (xx < NPX - 1) + (yy > 0) + (yy < NPY - 1);
        float dinvn = rsqrtf(degn);
        xwf(xx, yy, tmp);
        s0 = fmaf(dinvn, tmp[0], s0);
        s1 = fmaf(dinvn, tmp[1], s1);
        s2 = fmaf(dinvn, tmp[2], s2);
    };
    if (x > 0)       addn(x - 1, y);
    if (x < NPX - 1) addn(x + 1, y);
    if (y > 0)       addn(x, y - 1);
    if (y < NPY - 1) addn(x, y + 1);

    float self[3];
    xwf(x, y, self);
    float inv_deg = 1.f / degc;
    out[(size_t)idx * 3 + 0] = fmaf(dinvc, s0, self[0] * inv_deg) + bg[0];
    out[(size_t)idx * 3 + 1] = fmaf(dinvc, s1, self[1] * inv_deg) + bg[1];
    out[(size_t)idx * 3 + 2] = fmaf(dinvc, s2, self[2] * inv_deg) + bg[2];
}

// ---------------------------------------------------------------------------
extern "C" void kernel_launch(void* const* d_in, const int* in_sizes, int n_in,
                              void* d_out, int out_size, void* d_ws, size_t ws_size,
                              hipStream_t stream) {
    const float* pv = (const float*)d_in[0];
    const float* W1 = (const float*)d_in[1];
    const float* b1 = (const float*)d_in[2];
    const float* W2 = (const float*)d_in[3];
    const float* b2 = (const float*)d_in[4];
    const float* Wg = (const float*)d_in[5];
    const float* bg = (const float*)d_in[6];
    // d_in[7] = edge_index: fixed 4-neighbor grid, derived analytically

    float* ws = (float*)d_ws;
    float* out = (float*)d_out;
    bf16_t* W1T = (bf16_t*)(ws + OFF_W1T);

    hipLaunchKernelGGL(precompute_kernel, dim3(1), dim3(512), 0, stream,
                       W2, b2, Wg, ws);
    hipLaunchKernelGGL(w1t_kernel, dim3(16, 8), dim3(256), 0, stream,
                       W1, W1T);
    hipLaunchKernelGGL(gemm_mfma_kernel, dim3(M_ROWS / BM, N1 / BN), dim3(256), 0, stream,
                       pv, W1T, b1, ws, ws + OFF_HWPART);
    hipLaunchKernelGGL(hw_reduce_kernel, dim3((M_ROWS * 3 + 255) / 256), dim3(256), 0, stream,
                       ws);
    hipLaunchKernelGGL(stencil_kernel, dim3((BDIM * NPX * NPY + 255) / 256), dim3(256), 0, stream,
                       ws, Wg, bg, out);
}